// Round 1
// baseline (690.639 us; speedup 1.0000x reference)
//
#include <hip/hip_runtime.h>
#include <hip/hip_bf16.h>

#define B_DIM 32
#define L_DIM 512
#define D_DIM 768
#define N_PROMPT 20
#define D4 (D_DIM / 4)          // 192 float4 per (b,l) row
#define TOTAL4 (B_DIM * L_DIM * D4)   // 3,145,728 float4 elements

// Kernel 1: per-row pad-rank scan (one wave64 per batch row).
// Writes src[b*L+l] = rank (0..19) if this slot takes a prompt row, else -1.
// Also writes the attention_mask output (as float, d_out is a float buffer).
__global__ void prompt_scan_kernel(const int* __restrict__ mask,
                                   int* __restrict__ src,
                                   float* __restrict__ out_mask) {
    const int b = blockIdx.x;          // 0..31
    const int lane = threadIdx.x;      // 0..63
    int base = 0;                      // running pad count in this row
    const int row_off = b * L_DIM;
    for (int chunk = 0; chunk < L_DIM; chunk += 64) {
        const int l = chunk + lane;
        const int m = mask[row_off + l];
        const bool pad = (m == 0);
        const unsigned long long bal = __ballot(pad);
        const unsigned long long lower_mask =
            (lane == 0) ? 0ULL : (bal & ((1ULL << lane) - 1ULL));
        const int rank = base + __popcll(lower_mask);   // 0-based among pads
        const bool take = pad && (rank < N_PROMPT);
        src[row_off + l] = take ? rank : -1;
        out_mask[row_off + l] = take ? 1.0f : (float)m;
        base += __popcll(bal);
    }
}

// Kernel 2: vectorized select/copy of the embeddings.
__global__ void prompt_copy_kernel(const float4* __restrict__ in_embeds,
                                   const float4* __restrict__ prompts,
                                   const int* __restrict__ sids,
                                   const int* __restrict__ src,
                                   float4* __restrict__ out) {
    int idx = blockIdx.x * blockDim.x + threadIdx.x;
    const int stride = gridDim.x * blockDim.x;
    for (; idx < TOTAL4; idx += stride) {
        const int pos = idx / D4;       // (b,l) flat index
        const int d = idx - pos * D4;   // float4 index within the row
        const int s = src[pos];         // broadcast within the 192-thread group
        float4 v;
        if (s >= 0) {
            const int b = pos / L_DIM;
            const int sid = sids[b];
            v = prompts[((size_t)sid * N_PROMPT + s) * D4 + d];
        } else {
            v = in_embeds[idx];
        }
        out[idx] = v;
    }
}

extern "C" void kernel_launch(void* const* d_in, const int* in_sizes, int n_in,
                              void* d_out, int out_size, void* d_ws, size_t ws_size,
                              hipStream_t stream) {
    const int*   sids     = (const int*)d_in[0];            // [B] sample ids
    const float* embeds   = (const float*)d_in[1];          // [B,L,D]
    const int*   mask     = (const int*)d_in[2];            // [B,L]
    const float* prompts  = (const float*)d_in[3];          // [N_SAMPLES, N_PROMPT, D]

    float* out_embeds = (float*)d_out;                      // [B,L,D] first
    float* out_mask   = out_embeds + (size_t)B_DIM * L_DIM * D_DIM;  // [B,L] after

    int* src = (int*)d_ws;                                  // [B*L] ints (64 KB)

    // Kernel 1: one wave per row
    prompt_scan_kernel<<<B_DIM, 64, 0, stream>>>(mask, src, out_mask);

    // Kernel 2: grid-stride float4 copy
    const int block = 256;
    const int grid = (TOTAL4 + block - 1) / block;          // 12288 blocks
    prompt_copy_kernel<<<grid, block, 0, stream>>>(
        (const float4*)embeds, (const float4*)prompts, sids, src,
        (float4*)out_embeds);
}